// Round 18
// baseline (6832.632 us; speedup 1.0000x reference)
//
#include <hip/hip_runtime.h>

#define BN 4096

// ===== R18: R10 naive kernel + F32 OUTPUT STORES =====
// d_out is f32[4096][32] (reference dtype!). All R6+ rounds wrote 16-bit shorts ->
// compared through garbage f32 words. Five bit-exact decodes (R11,R12,R13,R15,R17)
// confirm the f32 buffer; R10/R14/R16 values are consistent with mine==ref.

__device__ __forceinline__ float sigmoidf_(float x) { return 1.f / (1.f + __expf(-x)); }
__device__ __forceinline__ float tanhf_(float x) {
    float ax = fabsf(x), e = __expf(-2.f * ax);
    float t = (1.f - e) / (1.f + e);
    return x < 0.f ? -t : t;
}

__global__ __launch_bounds__(256) void fill_out(float* out, float v) {
    int i = blockIdx.x * 256 + threadIdx.x;
    if (i < BN * 32) out[i] = v;
}

__global__ __launch_bounds__(256) void transpose_whh(const float* __restrict__ w, float* __restrict__ wt) {
    int i = blockIdx.x * 256 + threadIdx.x;   // 2048*512
    if (i < 2048 * 512) {
        int r = i >> 9, k = i & 511;
        wt[k * 2048 + r] = w[i];
    }
}
__global__ __launch_bounds__(256) void transpose_wih(const float* __restrict__ w, float* __restrict__ wt) {
    int i = blockIdx.x * 256 + threadIdx.x;   // 2048*28
    if (i < 2048 * 28) {
        int r = i / 28, c = i - r * 28;
        wt[c * 2048 + r] = w[i];
    }
}

__global__ __launch_bounds__(512) void naive_rnn(
    const float* __restrict__ input, const float* __restrict__ mask,
    const float* __restrict__ bias_mat,
    const float* __restrict__ w1, const float* __restrict__ b1,
    const float* __restrict__ cw, const float* __restrict__ cb,
    const float* __restrict__ wiT, const float* __restrict__ whT,
    const float* __restrict__ b_ih, const float* __restrict__ b_hh,
    const float* __restrict__ fc1w, const float* __restrict__ fc1b,
    const float* __restrict__ c2w, const float* __restrict__ c2b,
    float* __restrict__ out)
{
    __shared__ float sx[8][32][28];
    __shared__ float sh[8][512];
    __shared__ float scs[8][512];
    __shared__ float sctx[8][28];
    __shared__ float sua[8][32];

    const int tid = threadIdx.x;
    const int wv = tid >> 6, lane = tid & 63;
    const int row = blockIdx.x * 8 + wv;
    const float* inr = input + (size_t)row * 32 * 28;

    for (int o = lane; o < 896; o += 64) {
        int l = o / 28, c = o - (o / 28) * 28;
        float y = b1[c];
        for (int i = 0; i < 28; ++i) {
            float xm1 = (l > 0)  ? inr[(l - 1) * 28 + i] : 0.f;
            float x0  = inr[l * 28 + i];
            float xp1 = (l < 31) ? inr[(l + 1) * 28 + i] : 0.f;
            const float* w = w1 + c * 84 + i * 3;
            y += w[0] * xm1 + w[1] * x0 + w[2] * xp1;
        }
        y *= mask[row * 32 + l];
        float e = (y > 0.f) ? y : (__expf(y) - 1.f);   // ELU
        sx[wv][l][c] = e + inr[l * 28 + c];            // residual
    }
    for (int k = lane; k < 512; k += 64) { sh[wv][k] = 0.f; scs[wv][k] = 0.f; }
    __syncthreads();
    if (lane < 32) {
        float a = 0.f;
        for (int c = 0; c < 28; ++c) a += sx[wv][lane][c] * cw[c];
        sua[wv][lane] = (a + cb[0]) * mask[row * 32 + lane];
    }
    __syncthreads();

    const float bi_ = b_ih[0 * 512 + tid] + b_hh[0 * 512 + tid];
    const float bf_ = b_ih[1 * 512 + tid] + b_hh[1 * 512 + tid];
    const float bg_ = b_ih[2 * 512 + tid] + b_hh[2 * 512 + tid];
    const float bo_ = b_ih[3 * 512 + tid] + b_hh[3 * 512 + tid];

    for (int t = 0; t < 32; ++t) {
        // ---- A: attention ----
        float wa = 0.f;
        for (int k = lane; k < 512; k += 64) wa += sh[wv][k] * fc1w[k];
        #pragma unroll
        for (int off = 32; off; off >>= 1) wa += __shfl_xor(wa, off);
        wa += fc1b[0];
        int l32 = lane & 31;
        float e = sua[wv][l32] + wa;
        e = (e > 0.f) ? e : 0.01f * e;                 // leaky_relu
        e += bias_mat[row * 32 + l32];
        float mx = e;
        #pragma unroll
        for (int off = 16; off; off >>= 1) mx = fmaxf(mx, __shfl_xor(mx, off, 32));
        float ex = __expf(e - mx);
        float ss = ex;
        #pragma unroll
        for (int off = 16; off; off >>= 1) ss += __shfl_xor(ss, off, 32);
        float p = ex / ss;
        int cc = (lane < 28) ? lane : 0;
        float cv = 0.f;
        #pragma unroll
        for (int l = 0; l < 32; ++l) cv += __shfl(p, l) * sx[wv][l][cc];
        if (lane < 28) sctx[wv][lane] = cv;
        __syncthreads();

        // ---- B: gates; thread owns unit tid ----
        float pre[4][8];
        #pragma unroll
        for (int g = 0; g < 4; ++g)
            #pragma unroll
            for (int r = 0; r < 8; ++r) pre[g][r] = 0.f;
        for (int c = 0; c < 28; ++c) {
            float xr[8];
            #pragma unroll
            for (int r = 0; r < 8; ++r) xr[r] = sctx[r][c];
            const float* wc = wiT + c * 2048;
            #pragma unroll
            for (int g = 0; g < 4; ++g) {
                float wvv = wc[g * 512 + tid];
                #pragma unroll
                for (int r = 0; r < 8; ++r) pre[g][r] += wvv * xr[r];
            }
        }
        for (int k = 0; k < 512; ++k) {
            float hr[8];
            #pragma unroll
            for (int r = 0; r < 8; ++r) hr[r] = sh[r][k];
            const float* wk = whT + k * 2048;
            #pragma unroll
            for (int g = 0; g < 4; ++g) {
                float wvv = wk[g * 512 + tid];
                #pragma unroll
                for (int r = 0; r < 8; ++r) pre[g][r] += wvv * hr[r];
            }
        }
        __syncthreads();
        #pragma unroll
        for (int r = 0; r < 8; ++r) {
            float pi = pre[0][r] + bi_;
            float pf = pre[1][r] + bf_;
            float pg = pre[2][r] + bg_;
            float po = pre[3][r] + bo_;
            float c2 = sigmoidf_(pf) * scs[r][tid] + sigmoidf_(pi) * tanhf_(pg);
            scs[r][tid] = c2;
            sh[r][tid] = sigmoidf_(po) * tanhf_(c2);
        }
        __syncthreads();

        // ---- C: out[:, t]  (F32 STORE) ----
        float od = 0.f;
        for (int k = lane; k < 512; k += 64) od += sh[wv][k] * c2w[k];
        #pragma unroll
        for (int off = 32; off; off >>= 1) od += __shfl_xor(od, off);
        if (lane == 0)
            out[row * 32 + t] = (od + c2b[0]) * mask[row * 32 + t];
        __syncthreads();
    }
}

extern "C" void kernel_launch(void* const* d_in, const int* in_sizes, int n_in,
                              void* d_out, int out_size, void* d_ws, size_t ws_size,
                              hipStream_t stream)
{
    static const int exp_sizes[15] = {
        4096 * 32 * 28, 4096 * 32, 4096 * 32, 28 * 28 * 3, 28, 28, 1,
        2048 * 28, 2048 * 512, 2048, 2048, 512, 1, 512, 1
    };
    float* out = (float*)d_out;
    if (n_in != 15) { fill_out<<<512, 256, 0, stream>>>(out, 2000.f + n_in); return; }
    for (int i = 0; i < 15; ++i)
        if (in_sizes[i] != exp_sizes[i]) { fill_out<<<512, 256, 0, stream>>>(out, 1000.f + i); return; }
    if (out_size != BN * 32) { fill_out<<<512, 256, 0, stream>>>(out, 3000.f); return; }

    float* whT = (float*)d_ws;                 // [512][2048]
    float* wiT = whT + 2048 * 512;             // [28][2048]
    transpose_whh<<<(2048 * 512 + 255) / 256, 256, 0, stream>>>((const float*)d_in[8], whT);
    transpose_wih<<<(2048 * 28 + 255) / 256, 256, 0, stream>>>((const float*)d_in[7], wiT);

    naive_rnn<<<BN / 8, 512, 0, stream>>>(
        (const float*)d_in[0], (const float*)d_in[1], (const float*)d_in[2],
        (const float*)d_in[3], (const float*)d_in[4], (const float*)d_in[5], (const float*)d_in[6],
        wiT, whT, (const float*)d_in[9], (const float*)d_in[10],
        (const float*)d_in[11], (const float*)d_in[12], (const float*)d_in[13], (const float*)d_in[14],
        out);
}

// Round 20
// 1665.366 us; speedup vs baseline: 4.1028x; 4.1028x over previous
//
#include <hip/hip_runtime.h>
#include <hip/hip_bf16.h>

#define B_N 4096
#define L_N 32
#define C_N 28
#define H_N 512
#define T_N 32
#define G_N 2048     // 4*H
#define KP_N 544     // base K: 28 ctx + 4 pad + 512 h
#define KPA 1088     // A row: [hi(544) | lo(544)]

// R20: f32-accurate GEMM on matrix cores via bf16 hi/lo split (3-term).
// R19 (single bf16) validated all MFMA machinery; error 0.122 was quantization.
// K-extended: 34 chunks A[hi|lo] x W1=[Whi|Whi]  +  17 chunks A[hi] x W2=Wlo.

typedef __attribute__((ext_vector_type(4))) float f32x4;
typedef __attribute__((ext_vector_type(8))) short s16x8;

// workspace layout (bytes)
static constexpr size_t OFF_W1 = 0;                                   // W1 bf16 [2048][1088]
static constexpr size_t OFF_W2 = OFF_W1 + (size_t)G_N * KPA * 2;      // W2 bf16 [2048][544]
static constexpr size_t AB_ONE = (size_t)B_N * KPA * 2;               // one A buffer (8.9 MB)
static constexpr size_t OFF_AB = OFF_W2 + (size_t)G_N * KP_N * 2;     // A bf16 [2][4096][1088]
static constexpr size_t OFF_X  = OFF_AB + 2 * AB_ONE;                 // x f32 [4096][32][28]
static constexpr size_t OFF_UA = OFF_X + (size_t)B_N * L_N * C_N * 4; // u_a f32 [4096][32]
static constexpr size_t OFF_BS = OFF_UA + (size_t)B_N * L_N * 4;      // bsum f32 [2048] (8192 B)
static constexpr size_t OFF_CS = OFF_BS + 8192;                       // cstate f32 [4096][512]
static constexpr size_t WS_NEED = OFF_CS + (size_t)B_N * H_N * 4;     // ~48.1 MB

__device__ __forceinline__ float bf2f(short s) {
    union { unsigned int u; float f; } v;
    v.u = ((unsigned int)(unsigned short)s) << 16;
    return v.f;
}
__device__ __forceinline__ float sigmoidf_(float x) { return 1.f / (1.f + __expf(-x)); }
__device__ __forceinline__ float tanhf_(float x) {
    float ax = fabsf(x), e = __expf(-2.f * ax);
    float t = (1.f - e) / (1.f + e);
    return x < 0.f ? -t : t;
}
__device__ __forceinline__ void load16_lds(const void* g, void* l) {
    __builtin_amdgcn_global_load_lds((__attribute__((address_space(1))) void*)g,
                                     (__attribute__((address_space(3))) void*)l,
                                     16, 0, 0);
}

__global__ __launch_bounds__(256) void fill_out(float* out, float v) {
    int i = blockIdx.x * 256 + threadIdx.x;
    if (i < B_N * 32) out[i] = v;
}

// ---------------- precompute: conv1 residual block, x, u_a ----------------
__global__ void prep_x(const float* __restrict__ input, const float* __restrict__ mask,
                       const float* __restrict__ w1, const float* __restrict__ b1,
                       const float* __restrict__ cw, const float* __restrict__ cb,
                       float* __restrict__ x, float* __restrict__ ua)
{
    __shared__ float sw1[C_N * C_N * 3];
    __shared__ float sb1[C_N], scw[C_N];
    for (int i = threadIdx.x; i < C_N * C_N * 3; i += blockDim.x) sw1[i] = w1[i];
    if (threadIdx.x < C_N) { sb1[threadIdx.x] = b1[threadIdx.x]; scw[threadIdx.x] = cw[threadIdx.x]; }
    __syncthreads();
    int idx = blockIdx.x * blockDim.x + threadIdx.x;   // [0, B*L)
    if (idx >= B_N * L_N) return;
    int b = idx >> 5, l = idx & 31;
    float m = mask[idx];
    const float* inb = input + (size_t)b * (L_N * C_N);
    float xin[3][C_N];
    #pragma unroll
    for (int k = 0; k < 3; ++k) {
        int ll = l + k - 1;
        if (ll >= 0 && ll < L_N) {
            for (int c = 0; c < C_N; ++c) xin[k][c] = inb[ll * C_N + c];
        } else {
            for (int c = 0; c < C_N; ++c) xin[k][c] = 0.f;
        }
    }
    float uacc = 0.f;
    for (int o = 0; o < C_N; ++o) {
        float y = sb1[o];
        const float* wo = sw1 + o * (C_N * 3);
        for (int i = 0; i < C_N; ++i) {
            y += wo[i * 3 + 0] * xin[0][i];
            y += wo[i * 3 + 1] * xin[1][i];
            y += wo[i * 3 + 2] * xin[2][i];
        }
        y *= m;
        float e = (y > 0.f) ? y : (__expf(y) - 1.f);   // ELU
        float xv = e + xin[1][o];                      // residual
        x[(size_t)idx * C_N + o] = xv;
        uacc += xv * scw[o];
    }
    ua[idx] = (uacc + cb[0]) * m;
}

// ---------------- precompute: hi/lo split permuted weights + bias ----------------
// perm row p = unit*4 + gate (torch i,f,g,o); base cols [w_ih(28) | 0(4) | w_hh(512)]
__global__ void prep_w(const float* __restrict__ w_ih, const float* __restrict__ w_hh,
                       const float* __restrict__ b_ih, const float* __restrict__ b_hh,
                       __hip_bfloat16* __restrict__ W1, __hip_bfloat16* __restrict__ W2,
                       float* __restrict__ bsum)
{
    int p = blockIdx.x;            // [0,2048)
    int j = p >> 2, g = p & 3;
    int srow = g * H_N + j;
    for (int k = threadIdx.x; k < KP_N; k += blockDim.x) {
        float v;
        if (k < C_N) v = w_ih[srow * C_N + k];
        else if (k < 32) v = 0.f;
        else v = w_hh[(size_t)srow * H_N + (k - 32)];
        __hip_bfloat16 hi = __float2bfloat16(v);
        __hip_bfloat16 lo = __float2bfloat16(v - __bfloat162float(hi));
        W1[(size_t)p * KPA + k]        = hi;
        W1[(size_t)p * KPA + KP_N + k] = hi;
        W2[(size_t)p * KP_N + k]       = lo;
    }
    if (threadIdx.x == 0) bsum[p] = b_ih[srow] + b_hh[srow];
}

// ---------------- precompute: zero both A buffers + cstate ----------------
__global__ void prep_zero(unsigned int* __restrict__ a32, float* __restrict__ cst)
{
    int idx = blockIdx.x * blockDim.x + threadIdx.x;
    if (idx < B_N * KPA) a32[idx] = 0u;                // 2 bufs * B*KPA*2B / 4B = B*KPA words
    if (idx < B_N * H_N) cst[idx] = 0.f;
}

// ---------------- params ----------------
struct RParams {
    const float* mask;
    const float* bias_mat;
    const float* fc1_w;
    const float* fc1_b;
    const float* conv2_w;
    const float* conv2_b;
    const __hip_bfloat16* W1;
    const __hip_bfloat16* W2;
    const __hip_bfloat16* Ain;
    __hip_bfloat16* Aout;
    const float* x;
    const float* ua;
    const float* bsum;
    float* cstate;
    float* out;                  // F32 OUTPUT
};

// ---------------- attention step (one wave per batch row) ----------------
__global__ __launch_bounds__(256) void attn_step(RParams P, int t)
{
    const int tid  = threadIdx.x;
    const int lane = tid & 63;
    const int wave = tid >> 6;
    const int row  = blockIdx.x * 4 + wave;     // [0, 4096)

    const __hip_bfloat16* hrow = P.Ain + (size_t)row * KPA + 32;
    s16x8 hhi = *(const s16x8*)(hrow + lane * 8);
    s16x8 hlo = *(const s16x8*)(hrow + KP_N + lane * 8);
    float wadot = 0.f, odot = 0.f;
    const float* f1 = P.fc1_w + lane * 8;
    const float* c2 = P.conv2_w + lane * 8;
    #pragma unroll
    for (int q = 0; q < 8; ++q) {
        float hv = bf2f(hhi[q]) + bf2f(hlo[q]);       // ~f32-exact h
        wadot += f1[q] * hv;
        odot  += c2[q] * hv;
    }
    #pragma unroll
    for (int off = 32; off > 0; off >>= 1) {
        wadot += __shfl_xor(wadot, off);
        odot  += __shfl_xor(odot, off);
    }
    if (t > 0 && lane == 0)
        P.out[row * T_N + (t - 1)] = (odot + P.conv2_b[0]) * P.mask[row * L_N + (t - 1)];

    if (t < T_N) {
        float w_a = wadot + P.fc1_b[0];
        int l32 = lane & 31;
        float e = P.ua[row * L_N + l32] + w_a;
        e = (e > 0.f) ? e : 0.01f * e;              // leaky_relu
        e += P.bias_mat[row * L_N + l32];
        float mx = e;
        #pragma unroll
        for (int off = 16; off > 0; off >>= 1) mx = fmaxf(mx, __shfl_xor(mx, off, 32));
        float pexp = __expf(e - mx);
        float ssum = pexp;
        #pragma unroll
        for (int off = 16; off > 0; off >>= 1) ssum += __shfl_xor(ssum, off, 32);
        float p = pexp / ssum;
        int cc = (lane < C_N) ? lane : 0;
        const float* xrow = P.x + (size_t)row * (L_N * C_N) + cc;
        float ctx = 0.f;
        #pragma unroll
        for (int l = 0; l < L_N; ++l) {
            float al = __shfl(p, l);                // lanes 0..31 hold attn
            ctx += al * xrow[l * C_N];
        }
        if (lane < C_N) {
            __hip_bfloat16 hi = __float2bfloat16(ctx);
            __hip_bfloat16 lo = __float2bfloat16(ctx - __bfloat162float(hi));
            P.Aout[(size_t)row * KPA + lane]        = hi;
            P.Aout[(size_t)row * KPA + KP_N + lane] = lo;
        }
    }
}

// ---------------- gates GEMM [128x128, K=1088+544] MFMA + LSTM cell ----------------
__global__ __launch_bounds__(256) void gemm_cell_step(RParams P)
{
    __shared__ __align__(16) char smem[32768];   // A: 2x8K @0, W: 2x8K @16K; reused as gates 128x64 f32

    const int tid  = threadIdx.x;
    const int lane = tid & 63;
    const int wave = tid >> 6;         // 4 waves
    const int bid  = blockIdx.x;       // 512 WGs
    const int m    = bid >> 4;         // rows m*128..
    const int n    = bid & 15;         // perm cols n*128.., h-units n*32..
    const int wm   = wave >> 1, wn = wave & 1;

    const __hip_bfloat16* Ag  = P.Ain + (size_t)(m * 128) * KPA;
    const __hip_bfloat16* W1g = P.W1  + (size_t)(n * 128) * KPA;
    const __hip_bfloat16* W2g = P.W2  + (size_t)(n * 128) * KP_N;
    const int r4 = tid >> 2, c8 = (tid & 3) * 8;     // staging row/col within 128x32 tile
    const int sgA  = r4 * KPA  + c8;
    const int sgW1 = r4 * KPA  + c8;
    const int sgW2 = r4 * KP_N + c8;

    f32x4 acc[4][4];
    #pragma unroll
    for (int i = 0; i < 4; ++i)
        #pragma unroll
        for (int j2 = 0; j2 < 4; ++j2)
            acc[i][j2] = (f32x4){0.f, 0.f, 0.f, 0.f};

    // 51 chunks: kc<34 -> A[hi|lo] x W1=[Whi|Whi]; kc>=34 -> A[hi] x W2=Wlo
    auto stage = [&](int kc, int buf) {
        const __hip_bfloat16* agp;
        const __hip_bfloat16* bgp;
        size_t wstride;
        if (kc < 34) {
            agp = Ag + sgA + kc * 32;
            bgp = W1g + sgW1 + kc * 32;
            wstride = (size_t)64 * KPA;
        } else {
            agp = Ag + sgA + (kc - 34) * 32;          // hi region
            bgp = W2g + sgW2 + (kc - 34) * 32;
            wstride = (size_t)64 * KP_N;
        }
        load16_lds(agp,                     smem + buf * 8192 + tid * 16);
        load16_lds(agp + (size_t)64 * KPA,  smem + buf * 8192 + 4096 + tid * 16);
        load16_lds(bgp,                     smem + 16384 + buf * 8192 + tid * 16);
        load16_lds(bgp + wstride,           smem + 16384 + buf * 8192 + 4096 + tid * 16);
    };

    stage(0, 0);
    const int fo = ((lane & 15) * 32 + (lane >> 4) * 8) * 2;
    for (int kc = 0; kc < 51; ++kc) {
        __syncthreads();
        if (kc + 1 < 51) stage(kc + 1, (kc + 1) & 1);
        const char* Ab = smem + (kc & 1) * 8192;
        const char* Bb = smem + 16384 + (kc & 1) * 8192;
        s16x8 afr[4], bfr[4];
        #pragma unroll
        for (int i = 0; i < 4; ++i) {
            afr[i] = *(const s16x8*)(Ab + (wm * 64 + i * 16) * 64 + fo);
            bfr[i] = *(const s16x8*)(Bb + (wn * 64 + i * 16) * 64 + fo);
        }
        #pragma unroll
        for (int i = 0; i < 4; ++i)
            #pragma unroll
            for (int j2 = 0; j2 < 4; ++j2)
                acc[i][j2] = __builtin_amdgcn_mfma_f32_16x16x32_bf16(afr[i], bfr[j2], acc[i][j2], 0, 0, 0);
    }

    // ---- LSTM cell update, two 32KB halves through LDS ----
    __syncthreads();
    float* gates = (float*)smem;     // 128 rows x 64 cols f32
    #pragma unroll
    for (int hh = 0; hh < 2; ++hh) {
        if (wn == hh) {
            #pragma unroll
            for (int i = 0; i < 4; ++i)
                #pragma unroll
                for (int j2 = 0; j2 < 4; ++j2)
                    #pragma unroll
                    for (int r = 0; r < 4; ++r) {
                        int rowl = wm * 64 + i * 16 + (lane >> 4) * 4 + r;
                        int coll = j2 * 16 + (lane & 15);
                        gates[rowl * 64 + coll] = acc[i][j2][r];
                    }
        }
        __syncthreads();
        {
            int u = tid & 15, rr = tid >> 4;
            int unit = n * 32 + hh * 16 + u;
            f32x4 bsv = *(const f32x4*)(P.bsum + unit * 4);
            #pragma unroll
            for (int it = 0; it < 8; ++it) {
                int rowl = it * 16 + rr;
                int grow = m * 128 + rowl;
                f32x4 gv = *(const f32x4*)(gates + rowl * 64 + u * 4);
                float pi = gv.x + bsv.x;
                float pf = gv.y + bsv.y;
                float pg = gv.z + bsv.z;
                float po = gv.w + bsv.w;
                float* cp = P.cstate + (size_t)grow * H_N + unit;
                float c = sigmoidf_(pf) * (*cp) + sigmoidf_(pi) * tanhf_(pg);
                *cp = c;
                float h = sigmoidf_(po) * tanhf_(c);
                __hip_bfloat16 hi = __float2bfloat16(h);
                __hip_bfloat16 lo = __float2bfloat16(h - __bfloat162float(hi));
                P.Aout[(size_t)grow * KPA + 32 + unit]        = hi;
                P.Aout[(size_t)grow * KPA + KP_N + 32 + unit] = lo;
            }
        }
        __syncthreads();
    }
}

extern "C" void kernel_launch(void* const* d_in, const int* in_sizes, int n_in,
                              void* d_out, int out_size, void* d_ws, size_t ws_size,
                              hipStream_t stream)
{
    float* out = (float*)d_out;
    if (ws_size < WS_NEED) { fill_out<<<512, 256, 0, stream>>>(out, 4000.f); return; }

    const float* input = (const float*)d_in[0];
    const float* mask  = (const float*)d_in[1];
    const float* biasm = (const float*)d_in[2];
    const float* w1    = (const float*)d_in[3];
    const float* b1    = (const float*)d_in[4];
    const float* cw    = (const float*)d_in[5];
    const float* cb    = (const float*)d_in[6];
    const float* w_ih  = (const float*)d_in[7];
    const float* w_hh  = (const float*)d_in[8];
    const float* b_ih  = (const float*)d_in[9];
    const float* b_hh  = (const float*)d_in[10];
    const float* fc1w  = (const float*)d_in[11];
    const float* fc1b  = (const float*)d_in[12];
    const float* c2w   = (const float*)d_in[13];
    const float* c2b   = (const float*)d_in[14];

    char* ws = (char*)d_ws;
    __hip_bfloat16* W1    = (__hip_bfloat16*)(ws + OFF_W1);
    __hip_bfloat16* W2    = (__hip_bfloat16*)(ws + OFF_W2);
    __hip_bfloat16* Abuf0 = (__hip_bfloat16*)(ws + OFF_AB);
    __hip_bfloat16* Abuf1 = (__hip_bfloat16*)(ws + OFF_AB + AB_ONE);
    float* x    = (float*)(ws + OFF_X);
    float* ua   = (float*)(ws + OFF_UA);
    float* bsum = (float*)(ws + OFF_BS);
    float* cst  = (float*)(ws + OFF_CS);

    prep_x<<<(B_N * L_N) / 256, 256, 0, stream>>>(input, mask, w1, b1, cw, cb, x, ua);
    prep_w<<<G_N, 256, 0, stream>>>(w_ih, w_hh, b_ih, b_hh, W1, W2, bsum);
    prep_zero<<<(B_N * KPA + 255) / 256, 256, 0, stream>>>((unsigned int*)Abuf0, cst);

    RParams P;
    P.mask = mask; P.bias_mat = biasm; P.fc1_w = fc1w; P.fc1_b = fc1b;
    P.conv2_w = c2w; P.conv2_b = c2b; P.W1 = W1; P.W2 = W2;
    P.x = x; P.ua = ua; P.bsum = bsum; P.cstate = cst;
    P.out = out;

    __hip_bfloat16* bufs[2] = { Abuf0, Abuf1 };
    for (int t = 0; t < T_N; ++t) {
        P.Ain  = bufs[t & 1];
        P.Aout = bufs[t & 1];
        attn_step<<<B_N / 4, 256, 0, stream>>>(P, t);
        P.Ain  = bufs[t & 1];
        P.Aout = bufs[(t + 1) & 1];
        gemm_cell_step<<<512, 256, 0, stream>>>(P);
    }
    P.Ain  = bufs[T_N & 1];
    P.Aout = bufs[T_N & 1];
    attn_step<<<B_N / 4, 256, 0, stream>>>(P, T_N);   // out[:, T-1]
}